// Round 5
// baseline (2659.798 us; speedup 1.0000x reference)
//
#include <hip/hip_runtime.h>

// RGCN 2-layer graph encoder — R5: R4 atomic-free design + hb aliasing fix.
//  - edges counting-sorted by key = (dst_block(64), rel): 31,280 buckets,
//    each padded to a multiple of 16 (one MFMA tile of edges)
//  - one block owns 64 dst nodes exclusively; accumulates messages in a
//    padded LDS tile; epilogue: h = relu(h_root + acc), zero global atomics
//  - bf16 shadow buffers SPLIT: hb1 [N][EMB] layer-1 input (k_cvt_emb),
//    hb2 [N][HID] written by layer-1 epilogue, read by layer 2. (R4 aliased
//    these -> read/write race across concurrently-running blocks.)
//  - W_r fragments read directly from L2 (1.3 MB, per-XCD resident)

#define N_NODES 50000
#define N_EDGES 1200000
#define N_REL   40
#define N_BASES 30
#define EMB     64
#define HID     128
#define N_GRAPHS 64

#define DBLK    64                            // dst nodes per block
#define NDBLK   ((N_NODES + DBLK - 1) / DBLK) // 782
#define NKEY    (NDBLK * N_REL)               // 31280
#define PERM_CAP ((size_t)N_EDGES + (size_t)NKEY * 15)

typedef float f32x4  __attribute__((ext_vector_type(4)));
typedef short bf16x8 __attribute__((ext_vector_type(8)));

__device__ __forceinline__ unsigned short f2bf(float x) {
    unsigned int u = __float_as_uint(x);
    u = (u + 0x7FFFu + ((u >> 16) & 1u)) >> 16;   // RNE
    return (unsigned short)u;
}

// ---------------- workspace layout (float units) ----------------
#define OFF_WF1   ((size_t)0)                            // R*EMB*HID bf16
#define OFF_WF2   (OFF_WF1 + (size_t)N_REL*EMB*HID/2)
#define OFF_CNT   (OFF_WF2 + (size_t)N_REL*HID*HID/2)    // N*R f32
#define OFF_H1    (OFF_CNT + (size_t)N_NODES*N_REL)
#define OFF_H2    (OFF_H1 + (size_t)N_NODES*HID)
#define OFF_HB1   (OFF_H2 + (size_t)N_NODES*HID)         // N*EMB bf16 (layer-1 in)
#define OFF_HB2   (OFF_HB1 + (size_t)N_NODES*EMB/2)      // N*HID bf16 (layer-2 in)
#define OFF_CNTG  (OFF_HB2 + (size_t)N_NODES*HID/2)
#define OFF_POOL  (OFF_CNTG + N_GRAPHS)
#define OFF_PERM  (OFF_POOL + (size_t)N_GRAPHS*HID)      // PERM_CAP ints
#define OFF_HIST  (OFF_PERM + PERM_CAP)                  // NKEY ints
#define OFF_CUR   (OFF_HIST + NKEY)                      // NKEY ints
#define OFF_PO    (OFF_CUR + NKEY)                       // NKEY+1 ints

// ---- W fragment generator: Wf[r][((ct*KT+kt)*64+lane)*8+j] =
//      bf16( sum_b comp[r,b]*basis[b, kt*32+(lane>>4)*8+j, ct*16+(lane&15)] )
template <int IN, int KT>
__global__ void k_Wfrag(const float* __restrict__ comp, const float* __restrict__ basis,
                        unsigned short* __restrict__ Wf) {
    const int FR = IN * HID;
    int idx = blockIdx.x * blockDim.x + threadIdx.x;
    if (idx >= N_REL * FR) return;
    int r = idx / FR, F = idx - r * FR;
    int j = F & 7, lane = (F >> 3) & 63, tt = F >> 9;
    int kt = tt % KT, ct = tt / KT;
    int k = kt * 32 + (lane >> 4) * 8 + j;
    int c = ct * 16 + (lane & 15);
    float s = 0.f;
#pragma unroll
    for (int b = 0; b < N_BASES; ++b)
        s += comp[r * N_BASES + b] * basis[((size_t)b * IN + k) * HID + c];
    Wf[idx] = f2bf(s);
}

__global__ void k_count(const int* __restrict__ dst, const int* __restrict__ etype,
                        float* __restrict__ cnt) {
    int e = blockIdx.x * blockDim.x + threadIdx.x;
    if (e >= N_EDGES) return;
    atomicAdd(&cnt[(size_t)dst[e] * N_REL + etype[e]], 1.0f);
}

// ---- (dst_block, rel) bucketing ----
__global__ void k_hist2(const int* __restrict__ dst, const int* __restrict__ etype,
                        int* __restrict__ hist) {
    int e = blockIdx.x * blockDim.x + threadIdx.x;
    if (e >= N_EDGES) return;
    int key = (dst[e] >> 6) * N_REL + etype[e];
    atomicAdd(&hist[key], 1);
}

// single-block scan over NKEY buckets, padding each to a multiple of 16
__global__ void k_scan2(const int* __restrict__ hist, int* __restrict__ po) {
    __shared__ int csum[256];
    int t = threadIdx.x;
    const int CH = (NKEY + 255) / 256;
    int k0 = t * CH, k1 = min(k0 + CH, NKEY);
    int s = 0;
    for (int k = k0; k < k1; ++k) s += ((hist[k] + 15) >> 4) << 4;
    csum[t] = s;
    __syncthreads();
    if (t == 0) {
        int acc = 0;
        for (int i = 0; i < 256; ++i) { int v = csum[i]; csum[i] = acc; acc += v; }
        po[NKEY] = acc;
    }
    __syncthreads();
    int base = csum[t];
    for (int k = k0; k < k1; ++k) {
        po[k] = base;
        base += ((hist[k] + 15) >> 4) << 4;
    }
}

__global__ void k_scatter3(const int* __restrict__ dst, const int* __restrict__ etype,
                           const int* __restrict__ po, int* __restrict__ cur,
                           int* __restrict__ perm) {
    int e = blockIdx.x * blockDim.x + threadIdx.x;
    if (e >= N_EDGES) return;
    int key = (dst[e] >> 6) * N_REL + etype[e];
    int pos = atomicAdd(&cur[key], 1);
    perm[po[key] + pos] = e;
}

// h_acc[n, o] = bias[o] + sum_i hin[row(n), i] * root[i, o]
template <int IN>
__global__ void k_root(const float* __restrict__ hin, const int* __restrict__ xmap,
                       const float* __restrict__ root, const float* __restrict__ bias,
                       float* __restrict__ hacc) {
    int n = blockIdx.x;
    int o = threadIdx.x;  // 128
    int row = xmap ? xmap[n] : n;
    const float* hr = hin + (size_t)row * IN;
    float s = bias[o];
#pragma unroll 8
    for (int i = 0; i < IN; ++i)
        s = fmaf(hr[i], root[i * HID + o], s);
    hacc[(size_t)n * HID + o] = s;
}

// ---- MFMA edge kernel, block = 64 dst nodes, LDS accumulation ----
// A: lane l holds hb[edge(l&15)][kt*32 + (l>>4)*8 + j]  (16B gathers)
// B: fragment-ordered W read from L2, coalesced 16B
// C: lane l, reg q -> edge row (l>>4)*4+q, col (l&15)+ct*16
template <int IN, int KT, bool WRITE_HB>
__global__ __launch_bounds__(256, 4)
void k_edge4(const unsigned short* __restrict__ hb_in, const int* __restrict__ src,
             const int* __restrict__ dst, const int* __restrict__ perm,
             const int* __restrict__ po, const unsigned short* __restrict__ Wf,
             const float* __restrict__ cnt, float* __restrict__ h,
             unsigned short* __restrict__ hb_out) {
    __shared__ float accL[DBLK][HID + 4];   // stride 132: 16B-aligned rows, bank-spread
    int b = blockIdx.x;
    const int* pob = po + b * N_REL;
    int pstart = pob[0];
    int pend = pob[N_REL];

    for (int i = threadIdx.x; i < DBLK * (HID + 4) / 4; i += 256)
        ((f32x4*)&accL[0][0])[i] = (f32x4){0.f, 0.f, 0.f, 0.f};
    __syncthreads();

    int l = threadIdx.x & 63, wv = threadIdx.x >> 6;
    int lrow = l & 15, lk = l >> 4;
    int ntile = (pend - pstart) >> 4;

    for (int t = wv; t < ntile; t += 4) {
        int tstart = pstart + t * 16;
        int r = 0;
        while (pob[r + 1] <= tstart) ++r;   // rel of this tile (<=40 scalar loads)

        int ev = perm[tstart + lrow];
        int rowA = 0, dloc = 0;
        float inv = 0.f;
        if (ev >= 0) {
            rowA = src[ev];
            int d = dst[ev];
            dloc = d - b * DBLK;
            inv = 1.0f / fmaxf(cnt[(size_t)d * N_REL + r], 1.0f);
        }
        bf16x8 a[KT];
        const unsigned short* hrow = hb_in + (size_t)rowA * IN + lk * 8;
#pragma unroll
        for (int kt = 0; kt < KT; ++kt)
            a[kt] = *(const bf16x8*)(hrow + kt * 32);

        const unsigned short* Wr = Wf + (size_t)r * (8 * KT * 64 * 8);
        f32x4 acc[8];
#pragma unroll
        for (int ct = 0; ct < 8; ++ct) acc[ct] = (f32x4){0.f, 0.f, 0.f, 0.f};
#pragma unroll
        for (int ct = 0; ct < 8; ++ct) {
#pragma unroll
            for (int kt = 0; kt < KT; ++kt) {
                bf16x8 bb = *(const bf16x8*)(Wr + ((size_t)(ct * KT + kt) * 64 + l) * 8);
                acc[ct] = __builtin_amdgcn_mfma_f32_16x16x32_bf16(a[kt], bb, acc[ct], 0, 0, 0);
            }
        }
        // merge rows into the block-local LDS accumulator
#pragma unroll
        for (int q = 0; q < 4; ++q) {
            int row = lk * 4 + q;
            int e_q = __shfl(ev, row);
            if (e_q >= 0) {
                int dl    = __shfl(dloc, row);
                float i_q = __shfl(inv, row);
#pragma unroll
                for (int ct = 0; ct < 8; ++ct)
                    atomicAdd(&accL[dl][ct * 16 + lrow], acc[ct][q] * i_q);
            }
        }
    }
    __syncthreads();

    // epilogue: h = relu(h_root + acc); optional bf16 shadow to hb_out (distinct buffer!)
    int n0 = b * DBLK;
    for (int idx = threadIdx.x; idx < DBLK * (HID / 4); idx += 256) {
        int row = idx >> 5, c4 = (idx & 31) << 2;
        int n = n0 + row;
        if (n < N_NODES) {
            float* hp = h + (size_t)n * HID + c4;
            f32x4 v = *(const f32x4*)hp;
            f32x4 m = *(const f32x4*)&accL[row][c4];
            v.x = fmaxf(v.x + m.x, 0.f);
            v.y = fmaxf(v.y + m.y, 0.f);
            v.z = fmaxf(v.z + m.z, 0.f);
            v.w = fmaxf(v.w + m.w, 0.f);
            *(f32x4*)hp = v;
            if (WRITE_HB) {
                ushort4 o = {f2bf(v.x), f2bf(v.y), f2bf(v.z), f2bf(v.w)};
                *(ushort4*)(hb_out + (size_t)n * HID + c4) = o;
            }
        }
    }
}

// layer-1 A source: hb1[n][:] = bf16(node_emb[x[n]][:])
__global__ void k_cvt_emb(const float* __restrict__ emb, const int* __restrict__ x,
                          unsigned short* __restrict__ hb) {
    int idx = blockIdx.x * blockDim.x + threadIdx.x;
    if (idx >= N_NODES * (EMB / 4)) return;
    int n = idx / (EMB / 4), c4 = idx % (EMB / 4);
    int row = x[n];
    float4 v = *(const float4*)(emb + (size_t)row * EMB + c4 * 4);
    ushort4 o = {f2bf(v.x), f2bf(v.y), f2bf(v.z), f2bf(v.w)};
    *(ushort4*)(hb + (size_t)n * EMB + c4 * 4) = o;
}

__global__ void k_gcount2(const int* __restrict__ batch, float* __restrict__ cntG) {
    int g = threadIdx.x;
    if (g >= N_GRAPHS) return;
    int lo = 0, hi = N_NODES;
    while (lo < hi) { int m = (lo + hi) >> 1; if (batch[m] < g) lo = m + 1; else hi = m; }
    int lb0 = lo;
    lo = 0; hi = N_NODES;
    while (lo < hi) { int m = (lo + hi) >> 1; if (batch[m] < g + 1) lo = m + 1; else hi = m; }
    cntG[g] = (float)(lo - lb0);
}

__global__ void k_pool(const float* __restrict__ h, const int* __restrict__ batch,
                       float* __restrict__ acc) {
    const int CH = 512;
    int n0 = blockIdx.x * CH;
    int o = threadIdx.x;  // 128
    int nend = min(n0 + CH, N_NODES);
    if (n0 >= N_NODES) return;
    int curg = batch[n0];
    float run = 0.f;
    for (int n = n0; n < nend; ++n) {
        int g = batch[n];
        if (g != curg) {
            atomicAdd(&acc[(size_t)curg * HID + o], run);
            run = 0.f;
            curg = g;
        }
        run += h[(size_t)n * HID + o];
    }
    atomicAdd(&acc[(size_t)curg * HID + o], run);
}

__global__ void k_final(const float* __restrict__ acc, const float* __restrict__ cntG,
                        float* __restrict__ out) {
    int idx = blockIdx.x * blockDim.x + threadIdx.x;
    if (idx >= N_GRAPHS * HID) return;
    int g = idx >> 7;
    out[idx] = acc[idx] / fmaxf(cntG[g], 1.0f);
}

extern "C" void kernel_launch(void* const* d_in, const int* in_sizes, int n_in,
                              void* d_out, int out_size, void* d_ws, size_t ws_size,
                              hipStream_t stream) {
    const int*   x         = (const int*)d_in[0];
    const int*   edge_index= (const int*)d_in[1];
    const int*   etype     = (const int*)d_in[2];
    const int*   batch     = (const int*)d_in[3];
    const float* node_emb  = (const float*)d_in[4];
    const float* comp1     = (const float*)d_in[5];
    const float* basis1    = (const float*)d_in[6];
    const float* root1     = (const float*)d_in[7];
    const float* bias1     = (const float*)d_in[8];
    const float* comp2     = (const float*)d_in[9];
    const float* basis2    = (const float*)d_in[10];
    const float* root2     = (const float*)d_in[11];
    const float* bias2     = (const float*)d_in[12];
    float* out = (float*)d_out;

    const int* src = edge_index;
    const int* dst = edge_index + N_EDGES;

    float* ws = (float*)d_ws;
    unsigned short* Wf1 = (unsigned short*)(ws + OFF_WF1);
    unsigned short* Wf2 = (unsigned short*)(ws + OFF_WF2);
    float* cnt  = ws + OFF_CNT;
    float* h1   = ws + OFF_H1;
    float* h2   = ws + OFF_H2;
    unsigned short* hb1 = (unsigned short*)(ws + OFF_HB1);
    unsigned short* hb2 = (unsigned short*)(ws + OFF_HB2);
    float* cntG = ws + OFF_CNTG;
    float* pool = ws + OFF_POOL;
    int*   perm = (int*)(ws + OFF_PERM);
    int*   hist = (int*)(ws + OFF_HIST);
    int*   cur  = (int*)(ws + OFF_CUR);
    int*   po   = (int*)(ws + OFF_PO);

    hipMemsetAsync(cnt, 0, (size_t)N_NODES * N_REL * sizeof(float), stream);
    hipMemsetAsync(cntG, 0, (size_t)(N_GRAPHS + N_GRAPHS * HID) * sizeof(float), stream);
    hipMemsetAsync(hist, 0, (size_t)2 * NKEY * sizeof(int), stream);   // hist + cur
    hipMemsetAsync(perm, 0xFF, PERM_CAP * sizeof(int), stream);

    // (dst_block, rel) bucketing
    k_hist2<<<(N_EDGES + 255) / 256, 256, 0, stream>>>(dst, etype, hist);
    k_scan2<<<1, 256, 0, stream>>>(hist, po);
    k_scatter3<<<(N_EDGES + 255) / 256, 256, 0, stream>>>(dst, etype, po, cur, perm);

    k_count<<<(N_EDGES + 255) / 256, 256, 0, stream>>>(dst, etype, cnt);

    // fragment-ordered bf16 weights
    k_Wfrag<EMB, 2><<<(N_REL * EMB * HID + 255) / 256, 256, 0, stream>>>(comp1, basis1, Wf1);
    k_Wfrag<HID, 4><<<(N_REL * HID * HID + 255) / 256, 256, 0, stream>>>(comp2, basis2, Wf2);

    // ---- layer 1 ----
    k_cvt_emb<<<(N_NODES * (EMB / 4) + 255) / 256, 256, 0, stream>>>(node_emb, x, hb1);
    k_root<EMB><<<N_NODES, HID, 0, stream>>>(node_emb, x, root1, bias1, h1);
    k_edge4<EMB, 2, true><<<NDBLK, 256, 0, stream>>>(hb1, src, dst, perm, po, Wf1, cnt, h1, hb2);

    // ---- layer 2 ----
    k_root<HID><<<N_NODES, HID, 0, stream>>>(h1, nullptr, root2, bias2, h2);
    k_edge4<HID, 4, false><<<NDBLK, 256, 0, stream>>>(hb2, src, dst, perm, po, Wf2, cnt, h2, nullptr);

    // ---- global mean pool ----
    k_gcount2<<<1, 64, 0, stream>>>(batch, cntG);
    k_pool<<<(N_NODES + 511) / 512, HID, 0, stream>>>(h2, batch, pool);
    k_final<<<(N_GRAPHS * HID + 255) / 256, 256, 0, stream>>>(pool, cntG, out);
}